// Round 1
// baseline (177.395 us; speedup 1.0000x reference)
//
#include <hip/hip_runtime.h>

constexpr int NBATCH = 2048;   // B*T
constexpr int N      = 128;    // nodes
constexpr int D4     = 16;     // D/4 = 64/4
constexpr int PITCH4 = 17;     // src/tgt LDS row pitch in float4 (68 floats)
constexpr float INVTAU = 20.0f;   // 1/0.05
constexpr float EPSF   = 1e-8f;
constexpr float MUF    = 1.0f / 128.0f;   // mu = nu = 1/N

// One block per batch. 256 threads: tx = t&15, ty = t>>4.
// Thread owns C-tile rows r_a = ty + 16a, cols c_b = tx + 16b (a,b in 0..7).
__global__ __launch_bounds__(256, 1)
void sinkhorn_batch(const float* __restrict__ srcg,
                    const float* __restrict__ tgtg,
                    float* __restrict__ lossg)
{
    // LDS: src[128][68] + tgt[128][68] (69632 B) -> reused as KT (64 KB) after GEMM
    __shared__ float sAB[2 * N * PITCH4 * 4];
    __shared__ float sK[N * N];                 // XOR-swizzled K, 64 KB
    __shared__ float sU[N], sV[N], sX2[N], sY2[N];
    __shared__ float sRed[4];

    const int t  = threadIdx.x;
    const int tx = t & 15;
    const int ty = t >> 4;
    const int bt = blockIdx.x;

    const float* sg = srcg + (size_t)bt * (N * 64);
    const float* tg = tgtg + (size_t)bt * (N * 64);

    float4* sA4 = reinterpret_cast<float4*>(sAB);
    float4* sB4 = reinterpret_cast<float4*>(sAB + N * PITCH4 * 4);

    // ---- phase 0: stage src/tgt (coalesced float4) ----
    #pragma unroll
    for (int it = 0; it < 8; ++it) {
        int f  = t + 256 * it;        // 0..2047 float4s
        int r  = f >> 4;
        int d4 = f & 15;
        sA4[r * PITCH4 + d4] = reinterpret_cast<const float4*>(sg)[f];
        sB4[r * PITCH4 + d4] = reinterpret_cast<const float4*>(tg)[f];
    }
    __syncthreads();

    // ---- phase 0.5: row norms x2, y2 ----
    {
        int r = t & 127;
        const float4* base = (t < 128) ? sA4 : sB4;
        float s = 0.f;
        #pragma unroll
        for (int d4 = 0; d4 < D4; ++d4) {
            float4 v = base[r * PITCH4 + d4];
            s += v.x * v.x + v.y * v.y + v.z * v.z + v.w * v.w;
        }
        if (t < 128) sX2[r] = s; else sY2[r] = s;
    }
    __syncthreads();

    // ---- phase 1: 8x8 register-tiled fp32 GEMM (xy) ----
    float acc[8][8];
    #pragma unroll
    for (int a = 0; a < 8; ++a)
        #pragma unroll
        for (int b = 0; b < 8; ++b) acc[a][b] = 0.f;

    for (int d4 = 0; d4 < D4; ++d4) {
        float4 av[8], bv[8];
        #pragma unroll
        for (int a = 0; a < 8; ++a) av[a] = sA4[(ty + 16 * a) * PITCH4 + d4];
        #pragma unroll
        for (int b = 0; b < 8; ++b) bv[b] = sB4[(tx + 16 * b) * PITCH4 + d4];
        #pragma unroll
        for (int a = 0; a < 8; ++a)
            #pragma unroll
            for (int b = 0; b < 8; ++b)
                acc[a][b] += av[a].x * bv[b].x + av[a].y * bv[b].y
                           + av[a].z * bv[b].z + av[a].w * bv[b].w;
    }

    float x2r[8], y2c[8];
    #pragma unroll
    for (int a = 0; a < 8; ++a) x2r[a] = sX2[ty + 16 * a];
    #pragma unroll
    for (int b = 0; b < 8; ++b) y2c[b] = sY2[tx + 16 * b];

    __syncthreads();   // src/tgt reads complete -> region reusable for KT

    float* sKT = sAB;

    // ---- phase 2: C (kept in regs) and K / KT (LDS, XOR-swizzled) ----
    #pragma unroll
    for (int a = 0; a < 8; ++a) {
        int r = ty + 16 * a;
        #pragma unroll
        for (int b = 0; b < 8; ++b) {
            int c = tx + 16 * b;
            float d2 = x2r[a] + y2c[b] - 2.f * acc[a][b];
            d2 = fmaxf(d2, 0.f);
            float cd = sqrtf(d2);
            acc[a][b] = cd;                       // C stays in registers
            float k = __expf(-INVTAU * cd);
            sK [r * N + (((c >> 2) ^ (r & 7)) << 2) + (c & 3)] = k;
            sKT[c * N + (((r >> 2) ^ (c & 7)) << 2) + (r & 3)] = k;
        }
    }

    if (t < N) sV[t] = 1.0f;
    __syncthreads();

    // ---- phase 3: Sinkhorn iterations (2 threads per row) ----
    const int i   = t >> 1;     // row index 0..127
    const int h   = t & 1;      // half: j-range [h*64, h*64+64)
    const int swz = i & 7;

    const float4* sK4  = reinterpret_cast<const float4*>(sK);
    const float4* sKT4 = reinterpret_cast<const float4*>(sKT);
    const float4* sV4  = reinterpret_cast<const float4*>(sV);
    const float4* sU4  = reinterpret_cast<const float4*>(sU);

    for (int iter = 0; iter < 5; ++iter) {
        // u_i = mu / (sum_j K[i][j] * v[j] + eps)
        float s = 0.f;
        #pragma unroll
        for (int j4 = 0; j4 < 16; ++j4) {
            int jj4 = h * 16 + j4;
            float4 kv = sK4[i * 32 + (jj4 ^ swz)];
            float4 vv = sV4[jj4];
            s += kv.x * vv.x + kv.y * vv.y + kv.z * vv.z + kv.w * vv.w;
        }
        s += __shfl_xor(s, 1);
        if (h == 0) sU[i] = MUF / (s + EPSF);
        __syncthreads();

        // v_j = nu / (sum_i K[i][j] * u[i] + eps)   (rows of KT)
        s = 0.f;
        #pragma unroll
        for (int i4 = 0; i4 < 16; ++i4) {
            int ii4 = h * 16 + i4;
            float4 kv = sKT4[i * 32 + (ii4 ^ swz)];
            float4 uv = sU4[ii4];
            s += kv.x * uv.x + kv.y * uv.y + kv.z * uv.z + kv.w * uv.w;
        }
        s += __shfl_xor(s, 1);
        if (h == 0) sV[i] = MUF / (s + EPSF);
        __syncthreads();
    }

    // ---- phase 4: loss = sum u_i K_ij v_j C_ij (C in regs, K recomputed) ----
    float ur[8], vc[8];
    #pragma unroll
    for (int a = 0; a < 8; ++a) ur[a] = sU[ty + 16 * a];
    #pragma unroll
    for (int b = 0; b < 8; ++b) vc[b] = sV[tx + 16 * b];

    float part = 0.f;
    #pragma unroll
    for (int a = 0; a < 8; ++a)
        #pragma unroll
        for (int b = 0; b < 8; ++b) {
            float cd = acc[a][b];
            part += ur[a] * __expf(-INVTAU * cd) * vc[b] * cd;
        }

    // deterministic block reduce: 64-lane shuffle tree, then 4 wave sums
    #pragma unroll
    for (int off = 32; off >= 1; off >>= 1)
        part += __shfl_xor(part, off);
    if ((t & 63) == 0) sRed[t >> 6] = part;
    __syncthreads();
    if (t == 0) lossg[bt] = sRed[0] + sRed[1] + sRed[2] + sRed[3];
}

// mean over 2048 per-frame losses -> d_out[0]
__global__ __launch_bounds__(256, 1)
void reduce_mean(const float* __restrict__ lossg, float* __restrict__ out)
{
    __shared__ float sRed[4];
    int t = threadIdx.x;
    float s = 0.f;
    #pragma unroll
    for (int it = 0; it < 8; ++it) s += lossg[t + 256 * it];
    #pragma unroll
    for (int off = 32; off >= 1; off >>= 1) s += __shfl_xor(s, off);
    if ((t & 63) == 0) sRed[t >> 6] = s;
    __syncthreads();
    if (t == 0) out[0] = (sRed[0] + sRed[1] + sRed[2] + sRed[3]) * (1.0f / 2048.0f);
}

extern "C" void kernel_launch(void* const* d_in, const int* in_sizes, int n_in,
                              void* d_out, int out_size, void* d_ws, size_t ws_size,
                              hipStream_t stream)
{
    const float* src = (const float*)d_in[0];
    const float* tgt = (const float*)d_in[1];
    float* ws = (float*)d_ws;                       // 2048 floats of scratch

    sinkhorn_batch<<<NBATCH, 256, 0, stream>>>(src, tgt, ws);
    reduce_mean<<<1, 256, 0, stream>>>(ws, (float*)d_out);
}

// Round 2
// 129.850 us; speedup vs baseline: 1.3662x; 1.3662x over previous
//
#include <hip/hip_runtime.h>

constexpr int NBATCH = 2048;   // B*T
constexpr int N      = 128;    // nodes
constexpr int D4     = 16;     // D/4 = 64/4
constexpr int PITCH4 = 17;     // src/tgt LDS row pitch in float4 (68 floats)
constexpr float INVTAU = 20.0f;   // 1/0.05
constexpr float EPSF   = 1e-8f;
constexpr float MUF    = 1.0f / 128.0f;   // mu = nu = 1/N

// One block per batch, 256 threads: tx = t&15, ty = t>>4.
// Thread owns C rows r_a = ty+16a, cols c_b = tx+16b (a,b in 0..7).
// C and K=exp(-C/tau) both live in registers (64+64 VGPR); LDS holds only
// the staged inputs (69.6 KB) + tiny u/v/partial buffers -> 2 blocks/CU.
__global__ __launch_bounds__(256, 2)
void sinkhorn_batch(const float* __restrict__ srcg,
                    const float* __restrict__ tgtg,
                    float* __restrict__ lossg)
{
    __shared__ float4 sA4[N * PITCH4];
    __shared__ float4 sB4[N * PITCH4];
    __shared__ float sU[N], sV[N], sX2[N], sY2[N];
    __shared__ float sPart[4][8][16];   // [wave][b][tx] column partials
    __shared__ float sRed[4];

    const int t  = threadIdx.x;
    const int tx = t & 15;
    const int ty = t >> 4;
    const int w  = t >> 6;
    const int bt = blockIdx.x;

    const float* sg = srcg + (size_t)bt * (N * 64);
    const float* tg = tgtg + (size_t)bt * (N * 64);

    // ---- phase 0: stage src/tgt (coalesced float4) ----
    #pragma unroll
    for (int it = 0; it < 8; ++it) {
        int f  = t + 256 * it;        // 0..2047 float4s
        int r  = f >> 4;
        int d4 = f & 15;
        sA4[r * PITCH4 + d4] = reinterpret_cast<const float4*>(sg)[f];
        sB4[r * PITCH4 + d4] = reinterpret_cast<const float4*>(tg)[f];
    }
    __syncthreads();

    // ---- phase 0.5: row norms ----
    {
        int r = t & 127;
        const float4* base = (t < 128) ? sA4 : sB4;
        float s = 0.f;
        #pragma unroll
        for (int d4 = 0; d4 < D4; ++d4) {
            float4 v = base[r * PITCH4 + d4];
            s += v.x * v.x + v.y * v.y + v.z * v.z + v.w * v.w;
        }
        if (t < 128) sX2[r] = s; else sY2[r] = s;
    }
    __syncthreads();

    // ---- phase 1: 8x8 register-tiled fp32 GEMM (xy) ----
    float acc[8][8];
    #pragma unroll
    for (int a = 0; a < 8; ++a)
        #pragma unroll
        for (int b = 0; b < 8; ++b) acc[a][b] = 0.f;

    for (int d4 = 0; d4 < D4; ++d4) {
        float4 av[8], bv[8];
        #pragma unroll
        for (int a = 0; a < 8; ++a) av[a] = sA4[(ty + 16 * a) * PITCH4 + d4];
        #pragma unroll
        for (int b = 0; b < 8; ++b) bv[b] = sB4[(tx + 16 * b) * PITCH4 + d4];
        #pragma unroll
        for (int a = 0; a < 8; ++a)
            #pragma unroll
            for (int b = 0; b < 8; ++b)
                acc[a][b] += av[a].x * bv[b].x + av[a].y * bv[b].y
                           + av[a].z * bv[b].z + av[a].w * bv[b].w;
    }

    float x2r[8], y2c[8];
    #pragma unroll
    for (int a = 0; a < 8; ++a) x2r[a] = sX2[ty + 16 * a];
    #pragma unroll
    for (int b = 0; b < 8; ++b) y2c[b] = sY2[tx + 16 * b];

    // ---- phase 2: C (regs) and K = exp(-C/tau) (regs) ----
    float kk[8][8];
    #pragma unroll
    for (int a = 0; a < 8; ++a)
        #pragma unroll
        for (int b = 0; b < 8; ++b) {
            float d2 = x2r[a] + y2c[b] - 2.f * acc[a][b];
            float cd = sqrtf(fmaxf(d2, 0.f));
            acc[a][b] = cd;
            kk[a][b]  = __expf(-INVTAU * cd);
        }

    if (t < N) sV[t] = 1.0f;
    __syncthreads();

    // ---- phase 3: Sinkhorn iterations, K register-resident ----
    for (int iter = 0; iter < 5; ++iter) {
        // u_i = mu / (sum_j K[i][j] v[j] + eps): reduce over tx (in-wave)
        float vv[8];
        #pragma unroll
        for (int b = 0; b < 8; ++b) vv[b] = sV[tx + 16 * b];
        #pragma unroll
        for (int a = 0; a < 8; ++a) {
            float p = 0.f;
            #pragma unroll
            for (int b = 0; b < 8; ++b) p += kk[a][b] * vv[b];
            p += __shfl_xor(p, 1);
            p += __shfl_xor(p, 2);
            p += __shfl_xor(p, 4);
            p += __shfl_xor(p, 8);
            if (tx == 0) sU[ty + 16 * a] = MUF / (p + EPSF);
        }
        __syncthreads();

        // v_j = nu / (sum_i K[i][j] u[i] + eps): reduce over ty
        float uu[8];
        #pragma unroll
        for (int a = 0; a < 8; ++a) uu[a] = sU[ty + 16 * a];
        #pragma unroll
        for (int b = 0; b < 8; ++b) {
            float q = 0.f;
            #pragma unroll
            for (int a = 0; a < 8; ++a) q += kk[a][b] * uu[a];
            q += __shfl_xor(q, 16);
            q += __shfl_xor(q, 32);
            if ((t & 63) < 16) sPart[w][b][tx] = q;   // lane holds tx = lane&15
        }
        __syncthreads();
        if (t < N) {
            int b = t >> 4, x = t & 15;
            float s = sPart[0][b][x] + sPart[1][b][x]
                    + sPart[2][b][x] + sPart[3][b][x];
            sV[t] = MUF / (s + EPSF);
        }
        __syncthreads();
    }

    // ---- phase 4: loss = sum u_i K_ij v_j C_ij (all register-resident) ----
    float ur[8], vc[8];
    #pragma unroll
    for (int a = 0; a < 8; ++a) ur[a] = sU[ty + 16 * a];
    #pragma unroll
    for (int b = 0; b < 8; ++b) vc[b] = sV[tx + 16 * b];

    float part = 0.f;
    #pragma unroll
    for (int a = 0; a < 8; ++a) {
        float rs = 0.f;
        #pragma unroll
        for (int b = 0; b < 8; ++b)
            rs += kk[a][b] * vc[b] * acc[a][b];
        part += ur[a] * rs;
    }

    // deterministic block reduce
    #pragma unroll
    for (int off = 32; off >= 1; off >>= 1)
        part += __shfl_xor(part, off);
    if ((t & 63) == 0) sRed[w] = part;
    __syncthreads();
    if (t == 0) lossg[bt] = sRed[0] + sRed[1] + sRed[2] + sRed[3];
}

// mean over 2048 per-frame losses -> d_out[0]
__global__ __launch_bounds__(256, 1)
void reduce_mean(const float* __restrict__ lossg, float* __restrict__ out)
{
    __shared__ float sRed[4];
    int t = threadIdx.x;
    float s = 0.f;
    #pragma unroll
    for (int it = 0; it < 8; ++it) s += lossg[t + 256 * it];
    #pragma unroll
    for (int off = 32; off >= 1; off >>= 1) s += __shfl_xor(s, off);
    if ((t & 63) == 0) sRed[t >> 6] = s;
    __syncthreads();
    if (t == 0) out[0] = (sRed[0] + sRed[1] + sRed[2] + sRed[3]) * (1.0f / 2048.0f);
}

extern "C" void kernel_launch(void* const* d_in, const int* in_sizes, int n_in,
                              void* d_out, int out_size, void* d_ws, size_t ws_size,
                              hipStream_t stream)
{
    const float* src = (const float*)d_in[0];
    const float* tgt = (const float*)d_in[1];
    float* ws = (float*)d_ws;                       // 2048 floats of scratch

    sinkhorn_batch<<<NBATCH, 256, 0, stream>>>(src, tgt, ws);
    reduce_mean<<<1, 256, 0, stream>>>(ws, (float*)d_out);
}

// Round 3
// 75.580 us; speedup vs baseline: 2.3471x; 1.7180x over previous
//
#include <hip/hip_runtime.h>

constexpr int NBATCH = 2048;   // B*T
constexpr int N      = 128;    // nodes
constexpr float INVTAU = 20.0f;   // 1/0.05
constexpr float EPSF   = 1e-8f;
constexpr float MUF    = 1.0f / 128.0f;   // mu = nu = 1/N

typedef __attribute__((ext_vector_type(8))) short short8;   // 8 x bf16 MFMA frag
typedef __attribute__((ext_vector_type(4))) float f32x4;    // MFMA accumulator

// fp32 -> bf16 (RNE) as raw ushort
static __device__ __forceinline__ ushort f2bf(float x) {
    union { float f; unsigned u; } v; v.f = x;
    unsigned r = v.u + 0x7FFFu + ((v.u >> 16) & 1u);
    return (ushort)(r >> 16);
}

// LDS bf16 tile layout, XOR-swizzled (T2): row r, k-element k lives at
// ushort index r*64 + (((k>>3) ^ (r&7)) << 3) + (k&7).
// MFMA fragment read (16 rows, stride 128 B) then lands on distinct 16B
// slots per row-octet -> 2-way bank aliasing only (free, m136).

__global__ __launch_bounds__(256, 3)
void sinkhorn_batch(const float* __restrict__ srcg,
                    const float* __restrict__ tgtg,
                    float* __restrict__ lossg)
{
    __shared__ ushort sA[N * 64];          // src bf16, swizzled  (16 KB)
    __shared__ ushort sB[N * 64];          // tgt bf16, swizzled  (16 KB)
    __shared__ float sX2[N], sY2[N], sU[N], sV[N];
    __shared__ float sPart[4][8][16];      // [wave][colTile][lx] partials
    __shared__ float sRed[4];

    const int t  = threadIdx.x;
    const int l  = t & 63;
    const int w  = t >> 6;       // wave 0..3: owns rows 32w .. 32w+31
    const int lx = l & 15;
    const int lh = l >> 4;       // 0..3
    const int bt = blockIdx.x;

    const float4* sg4 = reinterpret_cast<const float4*>(srcg + (size_t)bt * (N * 64));
    const float4* tg4 = reinterpret_cast<const float4*>(tgtg + (size_t)bt * (N * 64));

    // ---- phase 0: stage bf16 (swizzled) + fp32 row norms via shuffle ----
    #pragma unroll
    for (int it = 0; it < 8; ++it) {
        int f  = t + 256 * it;    // 0..2047 float4s; 16 consecutive lanes = one row
        int r  = f >> 4;
        int d4 = f & 15;
        float4 a = sg4[f];
        float4 b = tg4[f];
        float pa = a.x * a.x + a.y * a.y + a.z * a.z + a.w * a.w;
        float pb = b.x * b.x + b.y * b.y + b.z * b.z + b.w * b.w;
        pa += __shfl_xor(pa, 1); pa += __shfl_xor(pa, 2);
        pa += __shfl_xor(pa, 4); pa += __shfl_xor(pa, 8);
        pb += __shfl_xor(pb, 1); pb += __shfl_xor(pb, 2);
        pb += __shfl_xor(pb, 4); pb += __shfl_xor(pb, 8);
        if ((t & 15) == 0) { sX2[r] = pa; sY2[r] = pb; }
        int idx = r * 64 + (((d4 >> 1) ^ (r & 7)) << 3) + (d4 & 1) * 4;
        ushort4 ua; ua.x = f2bf(a.x); ua.y = f2bf(a.y); ua.z = f2bf(a.z); ua.w = f2bf(a.w);
        ushort4 ub; ub.x = f2bf(b.x); ub.y = f2bf(b.y); ub.z = f2bf(b.z); ub.w = f2bf(b.w);
        *reinterpret_cast<ushort4*>(&sA[idx]) = ua;
        *reinterpret_cast<ushort4*>(&sB[idx]) = ub;
    }
    __syncthreads();

    // ---- phase 1: xy = src . tgt^T via bf16 MFMA ----
    // Wave w: row tiles {2w, 2w+1} x col tiles 0..7; D = A(16x32) * B(32x16).
    // A-frag: lane holds src[16*tr + lx][k = 8*lh .. +7 (+32*k32)]
    // B-frag: lane holds tgt[16*tc + lx][same k span]  (B[k][col] = tgt[col][k])
    f32x4 acc[2][8];
    #pragma unroll
    for (int tt = 0; tt < 2; ++tt)
        #pragma unroll
        for (int tc = 0; tc < 8; ++tc)
            acc[tt][tc] = (f32x4){0.f, 0.f, 0.f, 0.f};

    #pragma unroll
    for (int k32 = 0; k32 < 2; ++k32) {
        short8 af[2];
        #pragma unroll
        for (int tt = 0; tt < 2; ++tt) {
            int r   = 32 * w + 16 * tt + lx;
            int idx = r * 64 + (((k32 * 4 + lh) ^ (r & 7)) << 3);
            af[tt] = *reinterpret_cast<const short8*>(&sA[idx]);
        }
        #pragma unroll
        for (int tc = 0; tc < 8; ++tc) {
            int r   = 16 * tc + lx;
            int idx = r * 64 + (((k32 * 4 + lh) ^ (r & 7)) << 3);
            short8 bf = *reinterpret_cast<const short8*>(&sB[idx]);
            acc[0][tc] = __builtin_amdgcn_mfma_f32_16x16x32_bf16(af[0], bf, acc[0][tc], 0, 0, 0);
            acc[1][tc] = __builtin_amdgcn_mfma_f32_16x16x32_bf16(af[1], bf, acc[1][tc], 0, 0, 0);
        }
    }

    // C/D layout (m89): row-in-tile = 4*lh + q, col-in-tile = lx.
    // Lane owns rows R[tt][q] = 32w + 16tt + 4lh + q, cols 16tc + lx.

    // ---- phase 2: C (regs) and K = exp(-C/tau) (regs) ----
    float x2r[2][4], y2c[8];
    #pragma unroll
    for (int tt = 0; tt < 2; ++tt)
        #pragma unroll
        for (int q = 0; q < 4; ++q)
            x2r[tt][q] = sX2[32 * w + 16 * tt + 4 * lh + q];
    #pragma unroll
    for (int tc = 0; tc < 8; ++tc) y2c[tc] = sY2[16 * tc + lx];

    float kk[2][8][4], cc[2][8][4];
    #pragma unroll
    for (int tt = 0; tt < 2; ++tt)
        #pragma unroll
        for (int tc = 0; tc < 8; ++tc)
            #pragma unroll
            for (int q = 0; q < 4; ++q) {
                float d2 = x2r[tt][q] + y2c[tc] - 2.0f * acc[tt][tc][q];
                float cd = sqrtf(fmaxf(d2, 0.f));
                cc[tt][tc][q] = cd;
                kk[tt][tc][q] = __expf(-INVTAU * cd);
            }

    if (t < N) sV[t] = 1.0f;
    __syncthreads();

    // ---- phase 3: Sinkhorn iterations, K register-resident ----
    for (int iter = 0; iter < 5; ++iter) {
        // u_i = mu / (sum_j K[i][j] v[j] + eps): reduce over cols (lx in-wave)
        float vv[8];
        #pragma unroll
        for (int tc = 0; tc < 8; ++tc) vv[tc] = sV[16 * tc + lx];
        #pragma unroll
        for (int tt = 0; tt < 2; ++tt)
            #pragma unroll
            for (int q = 0; q < 4; ++q) {
                float p = 0.f;
                #pragma unroll
                for (int tc = 0; tc < 8; ++tc) p += kk[tt][tc][q] * vv[tc];
                p += __shfl_xor(p, 1); p += __shfl_xor(p, 2);
                p += __shfl_xor(p, 4); p += __shfl_xor(p, 8);
                if (lx == 0) sU[32 * w + 16 * tt + 4 * lh + q] = MUF / (p + EPSF);
            }
        __syncthreads();

        // v_j = nu / (sum_i K[i][j] u[i] + eps): reduce over rows
        float uu[2][4];
        #pragma unroll
        for (int tt = 0; tt < 2; ++tt)
            #pragma unroll
            for (int q = 0; q < 4; ++q)
                uu[tt][q] = sU[32 * w + 16 * tt + 4 * lh + q];
        #pragma unroll
        for (int tc = 0; tc < 8; ++tc) {
            float qc = 0.f;
            #pragma unroll
            for (int tt = 0; tt < 2; ++tt)
                #pragma unroll
                for (int q = 0; q < 4; ++q)
                    qc += kk[tt][tc][q] * uu[tt][q];
            qc += __shfl_xor(qc, 16);
            qc += __shfl_xor(qc, 32);
            if (l < 16) sPart[w][tc][lx] = qc;
        }
        __syncthreads();
        if (t < N) {
            int b = t >> 4, x = t & 15;
            float s = sPart[0][b][x] + sPart[1][b][x]
                    + sPart[2][b][x] + sPart[3][b][x];
            sV[t] = MUF / (s + EPSF);
        }
        __syncthreads();
    }

    // ---- phase 4: loss = sum u_i K_ij C_ij v_j (all register-resident) ----
    float ur[2][4], vc[8];
    #pragma unroll
    for (int tt = 0; tt < 2; ++tt)
        #pragma unroll
        for (int q = 0; q < 4; ++q)
            ur[tt][q] = sU[32 * w + 16 * tt + 4 * lh + q];
    #pragma unroll
    for (int tc = 0; tc < 8; ++tc) vc[tc] = sV[16 * tc + lx];

    float part = 0.f;
    #pragma unroll
    for (int tt = 0; tt < 2; ++tt)
        #pragma unroll
        for (int tc = 0; tc < 8; ++tc) {
            float rs = 0.f;
            #pragma unroll
            for (int q = 0; q < 4; ++q)
                rs += ur[tt][q] * kk[tt][tc][q] * cc[tt][tc][q];
            part += rs * vc[tc];
        }

    // deterministic block reduce
    #pragma unroll
    for (int off = 32; off >= 1; off >>= 1)
        part += __shfl_xor(part, off);
    if ((t & 63) == 0) sRed[w] = part;
    __syncthreads();
    if (t == 0) lossg[bt] = sRed[0] + sRed[1] + sRed[2] + sRed[3];
}

// mean over 2048 per-frame losses -> d_out[0]
__global__ __launch_bounds__(256, 1)
void reduce_mean(const float* __restrict__ lossg, float* __restrict__ out)
{
    __shared__ float sRed[4];
    int t = threadIdx.x;
    float s = 0.f;
    #pragma unroll
    for (int it = 0; it < 8; ++it) s += lossg[t + 256 * it];
    #pragma unroll
    for (int off = 32; off >= 1; off >>= 1) s += __shfl_xor(s, off);
    if ((t & 63) == 0) sRed[t >> 6] = s;
    __syncthreads();
    if (t == 0) out[0] = (sRed[0] + sRed[1] + sRed[2] + sRed[3]) * (1.0f / 2048.0f);
}

extern "C" void kernel_launch(void* const* d_in, const int* in_sizes, int n_in,
                              void* d_out, int out_size, void* d_ws, size_t ws_size,
                              hipStream_t stream)
{
    const float* src = (const float*)d_in[0];
    const float* tgt = (const float*)d_in[1];
    float* ws = (float*)d_ws;                       // 2048 floats of scratch

    sinkhorn_batch<<<NBATCH, 256, 0, stream>>>(src, tgt, ws);
    reduce_mean<<<1, 256, 0, stream>>>(ws, (float*)d_out);
}

// Round 4
// 70.409 us; speedup vs baseline: 2.5195x; 1.0734x over previous
//
#include <hip/hip_runtime.h>
#include <hip/hip_bf16.h>

constexpr int NBATCH = 2048;   // B*T
constexpr int N      = 128;    // nodes
constexpr float INVTAU = 20.0f;   // 1/0.05
constexpr float EPSF   = 1e-8f;
constexpr float MUF    = 1.0f / 128.0f;   // mu = nu = 1/N

typedef __attribute__((ext_vector_type(8))) short short8;   // 8 x bf16 MFMA frag
typedef __attribute__((ext_vector_type(4))) float f32x4;    // MFMA accumulator

static __device__ __forceinline__ float fastrcp(float x) {
    return __builtin_amdgcn_rcpf(x);   // v_rcp_f32, ~1e-7 rel err
}

// LDS bf16 tile, XOR-swizzled: row r, k-elt k at ushort idx
//   r*64 + (((k>>3) ^ (r&7)) << 3) + (k&7)
// 512 threads = 8 waves; wave w owns C rows 16w..16w+15, all 128 cols.
// Lane (lx=l&15, lh=l>>4) owns rows 16w+4lh+q (q<4), cols 16tc+lx (tc<8).
__global__ __launch_bounds__(512, 4)   // 4 waves/EU -> 2 blocks/CU, VGPR cap 128
void sinkhorn_batch(const float* __restrict__ srcg,
                    const float* __restrict__ tgtg,
                    float* __restrict__ lossg)
{
    __shared__ ushort sA[N * 64];          // src bf16, swizzled (16 KB)
    __shared__ ushort sB[N * 64];          // tgt bf16, swizzled (16 KB)
    __shared__ float sX2[N], sY2[N], sV[N];
    __shared__ float sPart[8][8][16];      // [wave][colTile][lx] partials (4 KB)
    __shared__ float sRed[8];

    const int t  = threadIdx.x;
    const int l  = t & 63;
    const int w  = t >> 6;       // wave 0..7
    const int lx = l & 15;
    const int lh = l >> 4;       // 0..3
    const int bt = blockIdx.x;

    const float4* sg4 = reinterpret_cast<const float4*>(srcg + (size_t)bt * (N * 64));
    const float4* tg4 = reinterpret_cast<const float4*>(tgtg + (size_t)bt * (N * 64));

    // ---- phase 0: stage bf16 (swizzled) + fp32 row norms, fused butterfly ----
    #pragma unroll
    for (int it = 0; it < 4; ++it) {
        int f  = t + 512 * it;    // 0..2047 float4s; 16 consecutive lanes = one row
        int r  = f >> 4;
        int d4 = f & 15;
        float4 a = sg4[f];
        float4 b = tg4[f];
        float pa = a.x * a.x + a.y * a.y + a.z * a.z + a.w * a.w;
        float pb = b.x * b.x + b.y * b.y + b.z * b.z + b.w * b.w;
        // lanes g<8 accumulate pa, g>=8 accumulate pb (one exchange), then 8-lane tree
        float x = (lx & 8) ? pb : pa;
        float y = (lx & 8) ? pa : pb;
        x += __shfl_xor(y, 8);
        x += __shfl_xor(x, 1);
        x += __shfl_xor(x, 2);
        x += __shfl_xor(x, 4);
        if ((lx & 7) == 0) ((lx & 8) ? sY2 : sX2)[r] = x;

        int idx = r * 64 + (((d4 >> 1) ^ (r & 7)) << 3) + (d4 & 1) * 4;
        union { __hip_bfloat162 h[2]; ushort4 u; } ca, cb;
        ca.h[0] = __float22bfloat162_rn(make_float2(a.x, a.y));
        ca.h[1] = __float22bfloat162_rn(make_float2(a.z, a.w));
        cb.h[0] = __float22bfloat162_rn(make_float2(b.x, b.y));
        cb.h[1] = __float22bfloat162_rn(make_float2(b.z, b.w));
        *reinterpret_cast<ushort4*>(&sA[idx]) = ca.u;
        *reinterpret_cast<ushort4*>(&sB[idx]) = cb.u;
    }
    __syncthreads();

    // ---- phase 1: xy = src . tgt^T via bf16 MFMA (1 row tile x 8 col tiles) ----
    f32x4 acc[8];
    #pragma unroll
    for (int tc = 0; tc < 8; ++tc) acc[tc] = (f32x4){0.f, 0.f, 0.f, 0.f};

    #pragma unroll
    for (int k32 = 0; k32 < 2; ++k32) {
        int ra   = 16 * w + lx;
        int aidx = ra * 64 + (((k32 * 4 + lh) ^ (ra & 7)) << 3);
        short8 af = *reinterpret_cast<const short8*>(&sA[aidx]);
        #pragma unroll
        for (int tc = 0; tc < 8; ++tc) {
            int rb   = 16 * tc + lx;
            int bidx = rb * 64 + (((k32 * 4 + lh) ^ (rb & 7)) << 3);
            short8 bf = *reinterpret_cast<const short8*>(&sB[bidx]);
            acc[tc] = __builtin_amdgcn_mfma_f32_16x16x32_bf16(af, bf, acc[tc], 0, 0, 0);
        }
    }

    // ---- phase 2: C (regs) and K = exp(-C/tau) (regs) ----
    float x2r[4], y2c[8];
    #pragma unroll
    for (int q = 0; q < 4; ++q) x2r[q] = sX2[16 * w + 4 * lh + q];
    #pragma unroll
    for (int tc = 0; tc < 8; ++tc) y2c[tc] = sY2[16 * tc + lx];

    float kk[8][4], cc[8][4];
    #pragma unroll
    for (int tc = 0; tc < 8; ++tc)
        #pragma unroll
        for (int q = 0; q < 4; ++q) {
            float d2 = x2r[q] + y2c[tc] - 2.0f * acc[tc][q];
            float cd = sqrtf(fmaxf(d2, 0.f));
            cc[tc][q] = cd;
            kk[tc][q] = __expf(-INVTAU * cd);
        }

    if (t < N) sV[t] = 1.0f;
    __syncthreads();

    // ---- phase 3: Sinkhorn iterations; u register-resident (butterfly = allreduce) ----
    float uu[4];
    for (int iter = 0; iter < 5; ++iter) {
        // u_i = mu / (sum_j K[i][j] v[j] + eps): reduce over cols (lx in-wave)
        float vv[8];
        #pragma unroll
        for (int tc = 0; tc < 8; ++tc) vv[tc] = sV[16 * tc + lx];
        #pragma unroll
        for (int q = 0; q < 4; ++q) {
            float p = 0.f;
            #pragma unroll
            for (int tc = 0; tc < 8; ++tc) p += kk[tc][q] * vv[tc];
            p += __shfl_xor(p, 1);
            p += __shfl_xor(p, 2);
            p += __shfl_xor(p, 4);
            p += __shfl_xor(p, 8);
            uu[q] = MUF * fastrcp(p + EPSF);   // every lane holds full sum
        }
        // no barrier: u never touches LDS

        // v_j = nu / (sum_i K[i][j] u[i] + eps): reduce over rows
        #pragma unroll
        for (int tc = 0; tc < 8; ++tc) {
            float qc = 0.f;
            #pragma unroll
            for (int q = 0; q < 4; ++q) qc += kk[tc][q] * uu[q];
            qc += __shfl_xor(qc, 16);
            qc += __shfl_xor(qc, 32);
            if (l < 16) sPart[w][tc][lx] = qc;
        }
        __syncthreads();
        if (t < N) {
            int b = t >> 4, x = t & 15;
            float s = sPart[0][b][x] + sPart[1][b][x] + sPart[2][b][x] + sPart[3][b][x]
                    + sPart[4][b][x] + sPart[5][b][x] + sPart[6][b][x] + sPart[7][b][x];
            sV[t] = MUF * fastrcp(s + EPSF);
        }
        __syncthreads();
    }

    // ---- phase 4: loss = sum u_i K_ij C_ij v_j (u, K, C register-resident) ----
    float vc[8];
    #pragma unroll
    for (int tc = 0; tc < 8; ++tc) vc[tc] = sV[16 * tc + lx];

    float part = 0.f;
    #pragma unroll
    for (int tc = 0; tc < 8; ++tc) {
        float rs = 0.f;
        #pragma unroll
        for (int q = 0; q < 4; ++q)
            rs += uu[q] * kk[tc][q] * cc[tc][q];
        part += rs * vc[tc];
    }

    // deterministic block reduce
    #pragma unroll
    for (int off = 32; off >= 1; off >>= 1)
        part += __shfl_xor(part, off);
    if (l == 0) sRed[w] = part;
    __syncthreads();
    if (t == 0) {
        float s = 0.f;
        #pragma unroll
        for (int i = 0; i < 8; ++i) s += sRed[i];
        lossg[bt] = s;
    }
}

// mean over 2048 per-frame losses -> d_out[0]
__global__ __launch_bounds__(256, 1)
void reduce_mean(const float* __restrict__ lossg, float* __restrict__ out)
{
    __shared__ float sRed[4];
    int t = threadIdx.x;
    float s = 0.f;
    #pragma unroll
    for (int it = 0; it < 8; ++it) s += lossg[t + 256 * it];
    #pragma unroll
    for (int off = 32; off >= 1; off >>= 1) s += __shfl_xor(s, off);
    if ((t & 63) == 0) sRed[t >> 6] = s;
    __syncthreads();
    if (t == 0) out[0] = (sRed[0] + sRed[1] + sRed[2] + sRed[3]) * (1.0f / 2048.0f);
}

extern "C" void kernel_launch(void* const* d_in, const int* in_sizes, int n_in,
                              void* d_out, int out_size, void* d_ws, size_t ws_size,
                              hipStream_t stream)
{
    const float* src = (const float*)d_in[0];
    const float* tgt = (const float*)d_in[1];
    float* ws = (float*)d_ws;                       // 2048 floats of scratch

    sinkhorn_batch<<<NBATCH, 512, 0, stream>>>(src, tgt, ws);
    reduce_mean<<<1, 256, 0, stream>>>(ws, (float*)d_out);
}